// Round 1
// baseline (772.093 us; speedup 1.0000x reference)
//
#include <hip/hip_runtime.h>
#include <math.h>

// RowLSTM fused kernel, round 1 (fp32 correctness-first baseline).
// Geometry (fixed by the problem):
//   x: [B=16, C=64, H=128, W=128] fp32
//   conv_w: [O=256, C=64, kH=3, kW=1] fp32 (O = 4*Hc, Hc=64)
//   conv_b: [256]
//   out: [B, Hc=64, H, W] fp32
// gates[b,o,h,w] = bias[o] + sum_{c,kh} x[b,c,h-2+kh,w] * w[o,c,kh]  (rows <0 are zero)
// scan over w: c = sig(f)*c + sig(i)*tanh(g); out = sig(o)*tanh(c)

#define NB   16
#define NC   64
#define NH   128
#define NW   128
#define NHC  64
#define NO   256   // 4*NHC
#define NK   192   // NC*3
#define WC   32    // w-chunk width

__global__ __launch_bounds__(256, 2) void rowlstm_fused(
    const float* __restrict__ x,
    const float* __restrict__ wgt,
    const float* __restrict__ bias,
    float* __restrict__ out)
{
    // LDS: x patch (24 KiB) + gates (33.8 KiB, padded) + h-out bounce (8 KiB)
    __shared__ float xs[NK][WC];        // xs[k][w], k = c*3 + kh
    __shared__ float g4[4][NHC][WC + 1]; // +1 pad: recurrence reads stride-33
    __shared__ float ho[NHC][WC];

    const int tid = threadIdx.x;
    const int bh  = blockIdx.x;
    const int b   = bh >> 7;      // / NH
    const int h   = bh & (NH - 1);

    const float* xb = x + (size_t)b * NC * NH * NW;
    const int gate = tid >> 6;    // 0:i 1:f 2:o 3:g  (wave-uniform)
    const int hc   = tid & 63;
    const float bias_o = bias[tid];
    const float* wp = wgt + (size_t)tid * NK;   // this thread's 192 weights

    float c_state = 0.f;          // live only in tid < 64

    for (int w0 = 0; w0 < NW; w0 += WC) {
        // ---- stage x patch: rows h-2, h-1, h for all c, this w-chunk ----
        for (int idx = tid; idx < NK * WC; idx += 256) {
            const int w  = idx & (WC - 1);
            const int k  = idx >> 5;
            const int cc = k / 3;
            const int kh = k - 3 * cc;
            const int r  = h - 2 + kh;
            float v = 0.f;
            if (r >= 0) v = xb[((size_t)cc * NH + r) * NW + w0 + w];
            xs[k][w] = v;
        }
        __syncthreads();

        // ---- gate GEMV: thread 'tid' = output channel o, 32 w at once ----
        float acc[WC];
        #pragma unroll
        for (int w = 0; w < WC; ++w) acc[w] = bias_o;

        for (int k4 = 0; k4 < NK; k4 += 4) {
            const float4 wv = *(const float4*)(wp + k4);
            #pragma unroll
            for (int dk = 0; dk < 4; ++dk) {
                const float wk = (&wv.x)[dk];
                #pragma unroll
                for (int w = 0; w < WC; ++w)
                    acc[w] += wk * xs[k4 + dk][w];
            }
        }

        // ---- nonlinearity, write gates to LDS ----
        #pragma unroll
        for (int w = 0; w < WC; ++w) {
            float v = acc[w];
            if (gate == 3) v = tanhf(v);
            else           v = 1.f / (1.f + __expf(-v));
            g4[gate][hc][w] = v;
        }
        __syncthreads();

        // ---- LSTM recurrence over this chunk's w (threads 0..63, one per hc) ----
        if (tid < 64) {
            float cst = c_state;
            #pragma unroll
            for (int w = 0; w < WC; ++w) {
                const float iv = g4[0][tid][w];
                const float fv = g4[1][tid][w];
                const float ov = g4[2][tid][w];
                const float gv = g4[3][tid][w];
                cst = fv * cst + iv * gv;
                ho[tid][w] = ov * tanhf(cst);
            }
            c_state = cst;
        }
        __syncthreads();

        // ---- coalesced store via LDS bounce ----
        for (int idx = tid; idx < NHC * WC; idx += 256) {
            const int w  = idx & (WC - 1);
            const int ch = idx >> 5;
            out[(((size_t)b * NHC + ch) * NH + h) * NW + w0 + w] = ho[ch][w];
        }
        __syncthreads();  // before next chunk overwrites xs
    }
}

extern "C" void kernel_launch(void* const* d_in, const int* in_sizes, int n_in,
                              void* d_out, int out_size, void* d_ws, size_t ws_size,
                              hipStream_t stream) {
    const float* x    = (const float*)d_in[0];
    const float* wgt  = (const float*)d_in[1];
    const float* bias = (const float*)d_in[2];
    float* out = (float*)d_out;

    rowlstm_fused<<<NB * NH, 256, 0, stream>>>(x, wgt, bias, out);
}

// Round 2
// 302.056 us; speedup vs baseline: 2.5561x; 2.5561x over previous
//
#include <hip/hip_runtime.h>
#include <math.h>

// RowLSTM fused, round 2: conv gates via f16 MFMA (16x16x32), fp32 scan.
//   x: [B=16, C=64, H=128, W=128] fp32
//   conv_w: [O=256, C=64, kH=3] fp32, conv_b: [256]
//   out: [B, Hc=64, H, W] fp32
// Block = one (b,h). 4 waves; wave g owns gate g (output channels g*64..g*64+63).
// gates[o][w] = bias[o] + sum_k W[o][k] * xpatch[k][w],  k = 3*c + kh, K=192.
// MFMA A = weights (in registers, 4 m-frags x 6 k-frags), B = x patch (LDS, f16).

#define NB   16
#define NC   64
#define NH   128
#define NW   128
#define NHC  64
#define NO   256
#define NK   192
#define WC   32     // w-chunk
#define KP   200    // padded k extent (row = 400B: 16B-aligned, bank-stride 4 => 2-way only)

typedef _Float16 half8 __attribute__((ext_vector_type(8)));
typedef float    f32x4 __attribute__((ext_vector_type(4)));

__global__ __launch_bounds__(256, 2) void rowlstm_mfma(
    const float* __restrict__ x,
    const float* __restrict__ wgt,
    const float* __restrict__ bias,
    float* __restrict__ out)
{
    __shared__ _Float16 xs[WC][KP];       // x patch, [w][k], 12.8 KB
    __shared__ float g4[4][NHC][WC + 1];  // activated gates, 33.8 KB (pad: scan stride 33)
    __shared__ float ho[NHC][WC];         // h outputs, 8 KB

    const int tid  = threadIdx.x;
    const int wave = tid >> 6;            // == gate index (i,f,o,g)
    const int lane = tid & 63;
    const int l15  = lane & 15;
    const int l4   = lane >> 4;

    // XCD-aware swizzle: 2048 % 8 == 0, contiguous h per XCD -> L2 reuse of stencil rows
    int bid = blockIdx.x;
    bid = (bid & 7) * (NB * NH / 8) + (bid >> 3);
    const int b = bid >> 7;
    const int h = bid & (NH - 1);

    const float* xb = x + (size_t)b * NC * NH * NW;

    // ---- A fragments (weights), held in registers for the whole kernel ----
    // A[mi][kt]: lane holds W[o = wave*64 + mi*16 + l15][k = kt*32 + l4*8 + j], j=0..7
    half8 afrag[4][6];
    #pragma unroll
    for (int mi = 0; mi < 4; ++mi) {
        const float* wo = wgt + (size_t)(wave * 64 + mi * 16 + l15) * NK;
        #pragma unroll
        for (int kt = 0; kt < 6; ++kt) {
            const float4 v0 = *(const float4*)(wo + kt * 32 + l4 * 8);
            const float4 v1 = *(const float4*)(wo + kt * 32 + l4 * 8 + 4);
            half8 a;
            a[0] = (_Float16)v0.x; a[1] = (_Float16)v0.y;
            a[2] = (_Float16)v0.z; a[3] = (_Float16)v0.w;
            a[4] = (_Float16)v1.x; a[5] = (_Float16)v1.y;
            a[6] = (_Float16)v1.z; a[7] = (_Float16)v1.w;
            afrag[mi][kt] = a;
        }
    }

    // bias per D slot: D row m = l4*4 + j within each 16-row m-tile
    float bfr[4][4];
    #pragma unroll
    for (int mi = 0; mi < 4; ++mi)
        #pragma unroll
        for (int j = 0; j < 4; ++j)
            bfr[mi][j] = bias[wave * 64 + mi * 16 + l4 * 4 + j];

    float cstate = 0.f;  // valid in tid < 64 (tid == hc)

    for (int w0 = 0; w0 < NW; w0 += WC) {
        // ---- stage x patch -> f16 xs[w][k] (transposed), 1536 float4 loads / block ----
        for (int t = tid; t < NK * 8; t += 256) {
            const int w4 = (t & 7) * 4;
            const int k  = t >> 3;
            const int c  = k / 3;
            const int kh = k - 3 * c;
            const int r  = h - 2 + kh;
            float4 v = make_float4(0.f, 0.f, 0.f, 0.f);
            if (r >= 0)
                v = *(const float4*)(xb + ((size_t)c * NH + r) * NW + w0 + w4);
            xs[w4 + 0][k] = (_Float16)v.x;
            xs[w4 + 1][k] = (_Float16)v.y;
            xs[w4 + 2][k] = (_Float16)v.z;
            xs[w4 + 3][k] = (_Float16)v.w;
        }
        __syncthreads();

        // ---- MFMA: D[o][w] for this wave's 64 o x 32 w ----
        f32x4 acc[4][2];
        #pragma unroll
        for (int mi = 0; mi < 4; ++mi)
            #pragma unroll
            for (int ni = 0; ni < 2; ++ni)
                acc[mi][ni] = (f32x4){0.f, 0.f, 0.f, 0.f};

        #pragma unroll
        for (int kt = 0; kt < 6; ++kt) {
            #pragma unroll
            for (int ni = 0; ni < 2; ++ni) {
                // B frag: xs[w = ni*16 + l15][k = kt*32 + l4*8 .. +7] -> ds_read_b128
                const half8 bf = *(const half8*)&xs[ni * 16 + l15][kt * 32 + l4 * 8];
                #pragma unroll
                for (int mi = 0; mi < 4; ++mi)
                    acc[mi][ni] = __builtin_amdgcn_mfma_f32_16x16x32_f16(
                        afrag[mi][kt], bf, acc[mi][ni], 0, 0, 0);
            }
        }

        // ---- bias + activation (wave-uniform branch), write to g4 ----
        #pragma unroll
        for (int mi = 0; mi < 4; ++mi)
            #pragma unroll
            for (int ni = 0; ni < 2; ++ni)
                #pragma unroll
                for (int j = 0; j < 4; ++j) {
                    float v = acc[mi][ni][j] + bfr[mi][j];
                    v = (wave == 3) ? tanhf(v) : 1.f / (1.f + __expf(-v));
                    g4[wave][mi * 16 + l4 * 4 + j][ni * 16 + l15] = v;
                }
        __syncthreads();

        // ---- LSTM scan over this chunk (threads 0..63, one per hc) ----
        if (tid < 64) {
            float c = cstate;
            #pragma unroll
            for (int w = 0; w < WC; ++w) {
                const float iv = g4[0][tid][w];
                const float fv = g4[1][tid][w];
                const float ov = g4[2][tid][w];
                const float gv = g4[3][tid][w];
                c = fv * c + iv * gv;
                ho[tid][w] = ov * tanhf(c);
            }
            cstate = c;
        }
        __syncthreads();

        // ---- coalesced store ----
        for (int t = tid; t < NHC * WC; t += 256) {
            const int w  = t & (WC - 1);
            const int ch = t >> 5;
            out[(((size_t)b * NHC + ch) * NH + h) * NW + w0 + w] = ho[ch][w];
        }
        __syncthreads();  // xs reuse next chunk
    }
}

extern "C" void kernel_launch(void* const* d_in, const int* in_sizes, int n_in,
                              void* d_out, int out_size, void* d_ws, size_t ws_size,
                              hipStream_t stream) {
    const float* x    = (const float*)d_in[0];
    const float* wgt  = (const float*)d_in[1];
    const float* bias = (const float*)d_in[2];
    float* out = (float*)d_out;

    rowlstm_mfma<<<NB * NH, 256, 0, stream>>>(x, wgt, bias, out);
}